// Round 16
// baseline (374.645 us; speedup 1.0000x reference)
//
#include <hip/hip_runtime.h>
#include <hip/hip_bf16.h>
#include <math.h>
#include <stdint.h>

typedef unsigned short u16;
typedef __attribute__((ext_vector_type(8))) short bfrag;      // 8 bf16 = 4 VGPR
typedef __attribute__((ext_vector_type(4))) float f32x4;
typedef __attribute__((ext_vector_type(8))) unsigned short u16x8;
typedef __attribute__((ext_vector_type(4))) unsigned short u16x4;

#define BB 16
#define CC 128
#define HH 128
#define WW 128
#define EPSV 1e-5f
#define NEG 0.1f
#define PW 130           // padded width/height (1-px zero border)

__device__ __forceinline__ float bf2f(u16 u) {
    unsigned int x = ((unsigned int)u) << 16;
    return __builtin_bit_cast(float, x);
}
__device__ __forceinline__ u16 f2bf(float f) {   // RNE
    unsigned int x = __builtin_bit_cast(unsigned int, f);
    unsigned int r = x + 0x7fffu + ((x >> 16) & 1u);
    return (u16)(r >> 16);
}
__device__ __forceinline__ void gload_lds16(const void* g, void* l) {
    __builtin_amdgcn_global_load_lds(
        (const __attribute__((address_space(1))) void*)g,
        (__attribute__((address_space(3))) void*)l, 16, 0, 0);
}

// ---------------- merged prep kernel -----------------------------------
__global__ __launch_bounds__(256)
void prep_kernel(const float* __restrict__ x, float* __restrict__ stats,
                 const float* __restrict__ w1, const float* __restrict__ w2,
                 u16* __restrict__ w1t, u16* __restrict__ w2t,
                 u16* __restrict__ hact, u16* __restrict__ hbuf,
                 const float* __restrict__ te, const float* __restrict__ nfw,
                 const float* __restrict__ nfbias, const float* __restrict__ c1b,
                 float* __restrict__ biastot,
                 const float* __restrict__ kv, const float* __restrict__ kw1,
                 const float* __restrict__ kw2, float* __restrict__ kern_t) {
    __shared__ float rs[8];
    __shared__ float s_t1[64];
    const int blk = blockIdx.x;
    const int tid = threadIdx.x;

    if (blk < 512) {                                    // ---- gn_stats ----
        const int bg = blk;
        const float* base = x + (size_t)bg * 65536;
        float s1 = 0.f, s2 = 0.f;
        for (int i = tid; i < 16384; i += 256) {
            float4 v = *(const float4*)&base[i * 4];
            s1 += v.x + v.y + v.z + v.w;
            s2 += v.x * v.x + v.y * v.y + v.z * v.z + v.w * v.w;
        }
        #pragma unroll
        for (int off = 32; off > 0; off >>= 1) {
            s1 += __shfl_down(s1, off);
            s2 += __shfl_down(s2, off);
        }
        const int wid = tid >> 6, lane = tid & 63;
        if (lane == 0) { rs[wid * 2] = s1; rs[wid * 2 + 1] = s2; }
        __syncthreads();
        if (tid == 0) {
            s1 = rs[0] + rs[2] + rs[4] + rs[6];
            s2 = rs[1] + rs[3] + rs[5] + rs[7];
            float mean = s1 * (1.f / 65536.f);
            float var  = s2 * (1.f / 65536.f) - mean * mean;
            stats[2 * bg]     = mean;
            stats[2 * bg + 1] = rsqrtf(var + EPSV);
        }
    } else if (blk < 1088) {                            // ---- wconv ----
        int idx = (blk - 512) * 256 + tid;              // < 147456
        int e  = idx & 7;
        int co = (idx >> 3) & 127;
        int g  = (idx >> 10) & 3;
        int ck = (idx >> 12) & 3;
        int t  = idx >> 14;
        int src = (co * 128 + (ck * 32 + g * 8 + e)) * 9 + t;
        w1t[idx] = f2bf(w1[src]);
        w2t[idx] = f2bf(w2[src]);
    } else if (blk < 1604) {                            // ---- border ----
        int idx = (blk - 1088) * 256 + tid;             // < 132096
        int cg = idx & 15;
        int t = idx >> 4;
        int b = t / 516, e = t - b * 516;
        int y, xx;
        if (e < 130)      { y = 0;           xx = e; }
        else if (e < 260) { y = 129;         xx = e - 130; }
        else if (e < 388) { y = e - 260 + 1; xx = 0; }
        else              { y = e - 388 + 1; xx = 129; }
        size_t o = (((size_t)b * PW + y) * PW + xx) * 128 + cg * 8;
        u16x8 z = (u16x8)(u16)0;
        *(u16x8*)&hact[o] = z;
        *(u16x8*)&hbuf[o] = z;
    } else if (blk < 1612) {                            // ---- biastot ----
        int idx = (blk - 1604) * 256 + tid;             // < 2048
        const int b = idx >> 7, c = idx & 127;
        float s = nfbias[c] + c1b[c];
        for (int e = 0; e < 128; ++e) s += te[b * 128 + e] * nfw[c * 128 + e];
        biastot[idx] = s;
    } else {                                            // ---- kern_t ----
        const int b = blk - 1612;                       // one block per b
        if (tid < 64) {
            float s = 0.f;
            for (int e = 0; e < 64; ++e) s += kv[b * 64 + e] * kw1[tid * 64 + e];
            s_t1[tid] = s >= 0.f ? s : NEG * s;
        }
        __syncthreads();
        for (int i = tid; i < 1152; i += 256) {
            float s = 0.f;
            for (int e = 0; e < 64; ++e) s += s_t1[e] * kw2[(size_t)i * 64 + e];
            int c = i / 9, t = i - c * 9;
            kern_t[((size_t)b * 9 + t) * 128 + c] = s;
        }
    }
}

// -- GroupNorm apply + Swish, NCHW fp32 -> padded NHWC bf16 (LDS transpose) --
__global__ __launch_bounds__(256)
void gn_apply_kernel(const float* __restrict__ x, const float* __restrict__ gamma,
                     const float* __restrict__ beta, const float* __restrict__ stats,
                     u16* __restrict__ hact) {
    __shared__ u16 s_t[128 * 128];
    const int tid = threadIdx.x;
    const int y = blockIdx.x & 127, b = blockIdx.x >> 7;
    #pragma unroll
    for (int i = 0; i < 16; ++i) {
        int unit = (i << 8) + tid;              // (c, x-quad)
        int c = unit >> 5, xq = unit & 31, xx = xq * 4;
        float4 v = *(const float4*)&x[(((size_t)b * 128 + c) * 128 + y) * 128 + xx];
        int gi = b * 32 + (c >> 2);
        float mean = stats[2 * gi], rstd = stats[2 * gi + 1];
        float ga = gamma[c] * rstd, be = beta[c] - mean * ga;
        float a0 = v.x * ga + be, a1 = v.y * ga + be, a2 = v.z * ga + be, a3 = v.w * ga + be;
        a0 = a0 / (1.f + __expf(-a0)); a1 = a1 / (1.f + __expf(-a1));
        a2 = a2 / (1.f + __expf(-a2)); a3 = a3 / (1.f + __expf(-a3));
        int cs = c ^ ((xq & 15) << 3);          // bank swizzle, keeps 8-groups intact
        s_t[(xx + 0) * 128 + cs] = f2bf(a0);
        s_t[(xx + 1) * 128 + cs] = f2bf(a1);
        s_t[(xx + 2) * 128 + cs] = f2bf(a2);
        s_t[(xx + 3) * 128 + cs] = f2bf(a3);
    }
    __syncthreads();
    #pragma unroll
    for (int i = 0; i < 8; ++i) {
        int unit = (i << 8) + tid;              // (x, c-group)
        int xx = unit >> 4, c0 = (unit & 15) * 8;
        int c0s = c0 ^ (((xx >> 2) & 15) << 3);
        u16x8 v = *(const u16x8*)&s_t[xx * 128 + c0s];
        *(u16x8*)&hact[(((size_t)b * PW + y + 1) * PW + (xx + 1)) * 128 + c0] = v;
    }
}

// ---------------- conv1: low-register / high-occupancy variant -------------
// (round-15 verified; 8 waves x (32co x 64px), acc[2][4], 4 waves/SIMD)
__global__ __launch_bounds__(512, 4)
void conv1_mfma_kernel(const u16* __restrict__ act, const u16* __restrict__ wt,
                       const float* __restrict__ bias, u16* __restrict__ outh) {
    __shared__ __align__(16) u16 s_in[2][1024 * 8];

    const int tid = threadIdx.x;
    const int lane = tid & 63, wid = tid >> 6;
    const int wm = wid & 3, wq = wid >> 2;            // co-quarter(32), px-half(64)
    const int l15 = lane & 15, l4 = lane >> 4;

    const int bid0 = blockIdx.x;
    const int bid = ((bid0 & 7) << 8) | (bid0 >> 3);
    const int tx = bid & 7, ty = (bid >> 3) & 15, b = bid >> 7;
    const int x0 = tx * 16, y0 = ty * 8;

    f32x4 acc[2][4];
    #pragma unroll
    for (int mi = 0; mi < 2; ++mi)
        #pragma unroll
        for (int nj = 0; nj < 4; ++nj) acc[mi][nj] = (f32x4)(0.f);

    int in_vofs[2];
    #pragma unroll
    for (int r = 0; r < 2; ++r) {
        int slot = r * 512 + tid;
        if (slot > 719) slot = 719;
        int cik = slot / 180;
        int pos = slot - cik * 180;
        int row = pos / 18, col = pos - row * 18;
        in_vofs[r] = (row * PW + col) * 128 + cik * 8;
    }
    const u16* in_base = act + (((size_t)b * PW + y0) * PW + x0) * 128;

    auto stage_in = [&](int buf, int ci0) {
        #pragma unroll
        for (int r = 0; r < 2; ++r)
            gload_lds16(in_base + ci0 + in_vofs[r],
                        &s_in[buf][(size_t)(r * 512 + (wid << 6)) * 8]);
    };

    const u16* wlane = wt + l4 * 1024 + (wm * 32 + l15) * 8;
    const int bbase = (l4 * 180 + (wq * 4) * 18 + l15) * 8;

    stage_in(0, 0);
    asm volatile("s_waitcnt vmcnt(0)" ::: "memory");
    __builtin_amdgcn_s_barrier();
    __builtin_amdgcn_sched_barrier(0);

    #pragma unroll
    for (int c = 0; c < 4; ++c) {
        if (c > 0) {
            __builtin_amdgcn_s_barrier();
            __builtin_amdgcn_sched_barrier(0);
        }
        if (c < 3) stage_in((c + 1) & 1, (c + 1) * 32);
        __builtin_amdgcn_sched_barrier(0);

        const u16* sb = &s_in[c & 1][0];
        #pragma unroll
        for (int dyr = 0; dyr < 3; ++dyr) {
            #pragma unroll
            for (int dx = 0; dx < 3; ++dx) {
                const u16* wp = wlane + (size_t)(((dyr * 3 + dx) * 4 + c) * 4096);
                bfrag a0 = *(const bfrag*)(wp);
                bfrag a1 = *(const bfrag*)(wp + 128);
                const int bo = bbase + (dyr * 18 + dx) * 8;
                bfrag b0 = *(const bfrag*)&sb[bo];
                bfrag b1 = *(const bfrag*)&sb[bo + 144];
                bfrag b2 = *(const bfrag*)&sb[bo + 288];
                bfrag b3 = *(const bfrag*)&sb[bo + 432];

                __builtin_amdgcn_s_setprio(1);
                acc[0][0] = __builtin_amdgcn_mfma_f32_16x16x32_bf16(a0, b0, acc[0][0], 0, 0, 0);
                acc[0][1] = __builtin_amdgcn_mfma_f32_16x16x32_bf16(a0, b1, acc[0][1], 0, 0, 0);
                acc[0][2] = __builtin_amdgcn_mfma_f32_16x16x32_bf16(a0, b2, acc[0][2], 0, 0, 0);
                acc[0][3] = __builtin_amdgcn_mfma_f32_16x16x32_bf16(a0, b3, acc[0][3], 0, 0, 0);
                acc[1][0] = __builtin_amdgcn_mfma_f32_16x16x32_bf16(a1, b0, acc[1][0], 0, 0, 0);
                acc[1][1] = __builtin_amdgcn_mfma_f32_16x16x32_bf16(a1, b1, acc[1][1], 0, 0, 0);
                acc[1][2] = __builtin_amdgcn_mfma_f32_16x16x32_bf16(a1, b2, acc[1][2], 0, 0, 0);
                acc[1][3] = __builtin_amdgcn_mfma_f32_16x16x32_bf16(a1, b3, acc[1][3], 0, 0, 0);
                __builtin_amdgcn_s_setprio(0);
            }
        }
    }

    const float* bb = bias + b * 128;
    #pragma unroll
    for (int mi = 0; mi < 2; ++mi) {
        const int cb = wm * 32 + mi * 16 + l4 * 4;
        float4 bv4 = *(const float4*)&bb[cb];
        #pragma unroll
        for (int nj = 0; nj < 4; ++nj) {
            int y = y0 + wq * 4 + nj, xx = x0 + l15;
            u16x4 pk;
            pk[0] = f2bf(acc[mi][nj][0] + bv4.x);
            pk[1] = f2bf(acc[mi][nj][1] + bv4.y);
            pk[2] = f2bf(acc[mi][nj][2] + bv4.z);
            pk[3] = f2bf(acc[mi][nj][3] + bv4.w);
            *(u16x4*)&outh[(((size_t)b * PW + y + 1) * PW + (xx + 1)) * 128 + cb] = pk;
        }
    }
}

// ---- conv2 (FINAL): low-register / high-occupancy + fused dw + residual ---
// 8 waves x (32co x 64px); acc[2][4]=32 regs; dw[2][4][4]=32 regs (wave wm
// owns chunk wm's channels -> single chunk per wave). Weights global->VGPR.
// LDS: act dbuf 2x16KB + s_k 4.6KB. One barrier + counted vmcnt per chunk.
__global__ __launch_bounds__(512, 4)
void conv2_mfma_kernel(const u16* __restrict__ act, const u16* __restrict__ wt,
                       const float* __restrict__ bias, const float* __restrict__ kern_t,
                       const float* __restrict__ xres, float* __restrict__ outf) {
    __shared__ __align__(16) u16 s_in[2][1024 * 8];   // 32 KB
    __shared__ float s_k[1152];                       // 4.6 KB

    const int tid = threadIdx.x;
    const int lane = tid & 63, wid = tid >> 6;
    const int wm = wid & 3, wq = wid >> 2;            // co-quarter(32), px-half(64)
    const int l15 = lane & 15, l4 = lane >> 4;

    const int bid0 = blockIdx.x;
    const int bid = ((bid0 & 7) << 8) | (bid0 >> 3);
    const int tx = bid & 7, ty = (bid >> 3) & 15, b = bid >> 7;
    const int x0 = tx * 16, y0 = ty * 8;

    f32x4 acc[2][4];
    #pragma unroll
    for (int mi = 0; mi < 2; ++mi)
        #pragma unroll
        for (int nj = 0; nj < 4; ++nj) acc[mi][nj] = (f32x4)(0.f);

    float dw[2][4][4];                                // [mi][nj][j]
    #pragma unroll
    for (int a1 = 0; a1 < 2; ++a1)
        #pragma unroll
        for (int a2 = 0; a2 < 4; ++a2)
            #pragma unroll
            for (int a3 = 0; a3 < 4; ++a3) dw[a1][a2][a3] = 0.f;

    for (int i = tid; i < 1152; i += 512) s_k[i] = kern_t[(size_t)b * 1152 + i];
    __syncthreads();                                  // ledger starts clean

    int in_vofs[2];
    #pragma unroll
    for (int r = 0; r < 2; ++r) {
        int slot = r * 512 + tid;
        if (slot > 719) slot = 719;
        int cik = slot / 180;
        int pos = slot - cik * 180;
        int row = pos / 18, col = pos - row * 18;
        in_vofs[r] = (row * PW + col) * 128 + cik * 8;
    }
    const u16* in_base = act + (((size_t)b * PW + y0) * PW + x0) * 128;

    auto stage_in = [&](int buf, int ci0) {
        #pragma unroll
        for (int r = 0; r < 2; ++r)
            gload_lds16(in_base + ci0 + in_vofs[r],
                        &s_in[buf][(size_t)(r * 512 + (wid << 6)) * 8]);
    };

    const u16* wlane = wt + l4 * 1024 + (wm * 32 + l15) * 8;
    const int bbase = (l4 * 180 + (wq * 4) * 18 + l15) * 8;

    // fused depthwise taps: wave wm owns chunk wm's 32 channels x its 64 px
    auto dwcomp = [&](int ck, int dyr) {
        if (wm == ck) {
            const u16* sb = &s_in[ck & 1][0];
            #pragma unroll
            for (int mi = 0; mi < 2; ++mi) {
                const int cik = mi * 2 + (l4 >> 1);
                const int e0 = (l4 & 1) * 4;
                const int cb = ck * 32 + mi * 16 + l4 * 4;
                #pragma unroll
                for (int dx = 0; dx < 3; ++dx) {
                    const int tap = dyr * 3 + dx;
                    float4 kk = *(const float4*)&s_k[tap * 128 + cb];
                    #pragma unroll
                    for (int nj = 0; nj < 4; ++nj) {
                        const int row = wq * 4 + nj + dyr;
                        const int col = l15 + dx;
                        u16x4 hv = *(const u16x4*)
                            &sb[(cik * 180 + row * 18 + col) * 8 + e0];
                        dw[mi][nj][0] += bf2f(hv[0]) * kk.x;
                        dw[mi][nj][1] += bf2f(hv[1]) * kk.y;
                        dw[mi][nj][2] += bf2f(hv[2]) * kk.z;
                        dw[mi][nj][3] += bf2f(hv[3]) * kk.w;
                    }
                }
            }
        }
    };

    stage_in(0, 0);
    asm volatile("s_waitcnt vmcnt(0)" ::: "memory");
    __builtin_amdgcn_s_barrier();
    __builtin_amdgcn_sched_barrier(0);

    #pragma unroll
    for (int c = 0; c < 4; ++c) {
        if (c > 0) {
            __builtin_amdgcn_s_barrier();
            __builtin_amdgcn_sched_barrier(0);
        }
        if (c < 3) {
            stage_in((c + 1) & 1, (c + 1) * 32);
            asm volatile("s_waitcnt vmcnt(2)" ::: "memory");   // drain older stage
        } else {
            asm volatile("s_waitcnt vmcnt(0)" ::: "memory");
        }
        __builtin_amdgcn_sched_barrier(0);

        const u16* sb = &s_in[c & 1][0];
        #pragma unroll
        for (int dyr = 0; dyr < 3; ++dyr) {
            #pragma unroll
            for (int dx = 0; dx < 3; ++dx) {
                const u16* wp = wlane + (size_t)(((dyr * 3 + dx) * 4 + c) * 4096);
                bfrag a0 = *(const bfrag*)(wp);
                bfrag a1 = *(const bfrag*)(wp + 128);
                const int bo = bbase + (dyr * 18 + dx) * 8;
                bfrag b0 = *(const bfrag*)&sb[bo];
                bfrag b1 = *(const bfrag*)&sb[bo + 144];
                bfrag b2 = *(const bfrag*)&sb[bo + 288];
                bfrag b3 = *(const bfrag*)&sb[bo + 432];

                __builtin_amdgcn_s_setprio(1);
                acc[0][0] = __builtin_amdgcn_mfma_f32_16x16x32_bf16(a0, b0, acc[0][0], 0, 0, 0);
                acc[0][1] = __builtin_amdgcn_mfma_f32_16x16x32_bf16(a0, b1, acc[0][1], 0, 0, 0);
                acc[0][2] = __builtin_amdgcn_mfma_f32_16x16x32_bf16(a0, b2, acc[0][2], 0, 0, 0);
                acc[0][3] = __builtin_amdgcn_mfma_f32_16x16x32_bf16(a0, b3, acc[0][3], 0, 0, 0);
                acc[1][0] = __builtin_amdgcn_mfma_f32_16x16x32_bf16(a1, b0, acc[1][0], 0, 0, 0);
                acc[1][1] = __builtin_amdgcn_mfma_f32_16x16x32_bf16(a1, b1, acc[1][1], 0, 0, 0);
                acc[1][2] = __builtin_amdgcn_mfma_f32_16x16x32_bf16(a1, b2, acc[1][2], 0, 0, 0);
                acc[1][3] = __builtin_amdgcn_mfma_f32_16x16x32_bf16(a1, b3, acc[1][3], 0, 0, 0);
                __builtin_amdgcn_s_setprio(0);
            }
            dwcomp(c, dyr);
        }
    }

    // epilogue: out = conv + bias + leaky(dw) + xres (single coalesced write)
    #pragma unroll
    for (int mi = 0; mi < 2; ++mi) {
        const int cb = wm * 32 + mi * 16 + l4 * 4;
        float4 bv4 = *(const float4*)&bias[cb];
        #pragma unroll
        for (int nj = 0; nj < 4; ++nj) {
            int y = y0 + wq * 4 + nj, xx = x0 + l15;
            size_t obase = (((size_t)b * 128 + cb) * 128 + y) * 128 + xx;
            #pragma unroll
            for (int j = 0; j < 4; ++j) {
                float d = dw[mi][nj][j];
                d = d >= 0.f ? d : NEG * d;
                float bj = (j == 0) ? bv4.x : (j == 1) ? bv4.y : (j == 2) ? bv4.z : bv4.w;
                outf[obase + (size_t)j * 16384] =
                    acc[mi][nj][j] + bj + d + xres[obase + (size_t)j * 16384];
            }
        }
    }
}

extern "C" void kernel_launch(void* const* d_in, const int* in_sizes, int n_in,
                              void* d_out, int out_size, void* d_ws, size_t ws_size,
                              hipStream_t stream) {
    const float* x        = (const float*)d_in[0];
    const float* te       = (const float*)d_in[1];
    const float* kv       = (const float*)d_in[2];
    const float* gn1_g    = (const float*)d_in[3];
    const float* gn1_b    = (const float*)d_in[4];
    const float* conv1_w  = (const float*)d_in[5];
    const float* conv1_b  = (const float*)d_in[6];
    const float* nf_w     = (const float*)d_in[7];
    const float* nf_b     = (const float*)d_in[8];
    const float* kW1      = (const float*)d_in[9];
    const float* kW2      = (const float*)d_in[10];
    const float* daconv_w = (const float*)d_in[11];
    const float* daconv_b = (const float*)d_in[12];

    float* out = (float*)d_out;

    // workspace: kern_t, w2t, hbuf (padded)
    float* kern  = (float*)d_ws;                         // 18432 f32 ([b][tap][c])
    u16*   w2t   = (u16*)(kern + 18432);                 // 147456 u16
    u16*   hbuf  = (u16*)(kern + 92160);                 // 16*130*130*128 u16 (69.2 MB)

    // temps dead before conv2's overwrite of d_out
    u16*   hact    = (u16*)out;                          // padded NHWC
    float* up      = out + 17500160;
    float* stats   = up;                                 // 1024
    float* biastot = up + 1024;                          // 2048
    u16*   w1t     = (u16*)(up + 4096);                  // 147456 u16

    prep_kernel<<<dim3(1628), dim3(256), 0, stream>>>(
        x, stats, conv1_w, daconv_w, w1t, w2t, hact, hbuf,
        te, nf_w, nf_b, conv1_b, biastot, kv, kW1, kW2, kern);
    gn_apply_kernel<<<dim3(2048), dim3(256), 0, stream>>>(x, gn1_g, gn1_b, stats, hact);
    conv1_mfma_kernel<<<dim3(2048), dim3(512), 0, stream>>>(hact, w1t, biastot, hbuf);
    conv2_mfma_kernel<<<dim3(2048), dim3(512), 0, stream>>>(
        hbuf, w2t, daconv_b, kern, x, out);
}

// Round 17
// 359.165 us; speedup vs baseline: 1.0431x; 1.0431x over previous
//
#include <hip/hip_runtime.h>
#include <hip/hip_bf16.h>
#include <math.h>
#include <stdint.h>

typedef unsigned short u16;
typedef __attribute__((ext_vector_type(8))) short bfrag;      // 8 bf16 = 4 VGPR
typedef __attribute__((ext_vector_type(4))) float f32x4;
typedef __attribute__((ext_vector_type(8))) unsigned short u16x8;
typedef __attribute__((ext_vector_type(4))) unsigned short u16x4;

#define BB 16
#define CC 128
#define HH 128
#define WW 128
#define EPSV 1e-5f
#define NEG 0.1f
#define PW 130           // padded width/height (1-px zero border)

__device__ __forceinline__ float bf2f(u16 u) {
    unsigned int x = ((unsigned int)u) << 16;
    return __builtin_bit_cast(float, x);
}
__device__ __forceinline__ u16 f2bf(float f) {   // RNE
    unsigned int x = __builtin_bit_cast(unsigned int, f);
    unsigned int r = x + 0x7fffu + ((x >> 16) & 1u);
    return (u16)(r >> 16);
}
__device__ __forceinline__ void gload_lds16(const void* g, void* l) {
    __builtin_amdgcn_global_load_lds(
        (const __attribute__((address_space(1))) void*)g,
        (__attribute__((address_space(3))) void*)l, 16, 0, 0);
}

// ---------------- merged prep kernel -----------------------------------
__global__ __launch_bounds__(256)
void prep_kernel(const float* __restrict__ x, float* __restrict__ stats,
                 const float* __restrict__ w1, const float* __restrict__ w2,
                 u16* __restrict__ w1t, u16* __restrict__ w2t,
                 u16* __restrict__ hact, u16* __restrict__ hbuf,
                 const float* __restrict__ te, const float* __restrict__ nfw,
                 const float* __restrict__ nfbias, const float* __restrict__ c1b,
                 float* __restrict__ biastot,
                 const float* __restrict__ kv, const float* __restrict__ kw1,
                 const float* __restrict__ kw2, float* __restrict__ kern_t) {
    __shared__ float rs[8];
    __shared__ float s_t1[64];
    const int blk = blockIdx.x;
    const int tid = threadIdx.x;

    if (blk < 512) {                                    // ---- gn_stats ----
        const int bg = blk;
        const float* base = x + (size_t)bg * 65536;
        float s1 = 0.f, s2 = 0.f;
        for (int i = tid; i < 16384; i += 256) {
            float4 v = *(const float4*)&base[i * 4];
            s1 += v.x + v.y + v.z + v.w;
            s2 += v.x * v.x + v.y * v.y + v.z * v.z + v.w * v.w;
        }
        #pragma unroll
        for (int off = 32; off > 0; off >>= 1) {
            s1 += __shfl_down(s1, off);
            s2 += __shfl_down(s2, off);
        }
        const int wid = tid >> 6, lane = tid & 63;
        if (lane == 0) { rs[wid * 2] = s1; rs[wid * 2 + 1] = s2; }
        __syncthreads();
        if (tid == 0) {
            s1 = rs[0] + rs[2] + rs[4] + rs[6];
            s2 = rs[1] + rs[3] + rs[5] + rs[7];
            float mean = s1 * (1.f / 65536.f);
            float var  = s2 * (1.f / 65536.f) - mean * mean;
            stats[2 * bg]     = mean;
            stats[2 * bg + 1] = rsqrtf(var + EPSV);
        }
    } else if (blk < 1088) {                            // ---- wconv ----
        int idx = (blk - 512) * 256 + tid;              // < 147456
        int e  = idx & 7;
        int co = (idx >> 3) & 127;
        int g  = (idx >> 10) & 3;
        int ck = (idx >> 12) & 3;
        int t  = idx >> 14;
        int src = (co * 128 + (ck * 32 + g * 8 + e)) * 9 + t;
        w1t[idx] = f2bf(w1[src]);
        w2t[idx] = f2bf(w2[src]);
    } else if (blk < 1604) {                            // ---- border ----
        int idx = (blk - 1088) * 256 + tid;             // < 132096
        int cg = idx & 15;
        int t = idx >> 4;
        int b = t / 516, e = t - b * 516;
        int y, xx;
        if (e < 130)      { y = 0;           xx = e; }
        else if (e < 260) { y = 129;         xx = e - 130; }
        else if (e < 388) { y = e - 260 + 1; xx = 0; }
        else              { y = e - 388 + 1; xx = 129; }
        size_t o = (((size_t)b * PW + y) * PW + xx) * 128 + cg * 8;
        u16x8 z = (u16x8)(u16)0;
        *(u16x8*)&hact[o] = z;
        *(u16x8*)&hbuf[o] = z;
    } else if (blk < 1612) {                            // ---- biastot ----
        int idx = (blk - 1604) * 256 + tid;             // < 2048
        const int b = idx >> 7, c = idx & 127;
        float s = nfbias[c] + c1b[c];
        for (int e = 0; e < 128; ++e) s += te[b * 128 + e] * nfw[c * 128 + e];
        biastot[idx] = s;
    } else {                                            // ---- kern_t ----
        const int b = blk - 1612;                       // one block per b
        if (tid < 64) {
            float s = 0.f;
            for (int e = 0; e < 64; ++e) s += kv[b * 64 + e] * kw1[tid * 64 + e];
            s_t1[tid] = s >= 0.f ? s : NEG * s;
        }
        __syncthreads();
        for (int i = tid; i < 1152; i += 256) {
            float s = 0.f;
            for (int e = 0; e < 64; ++e) s += s_t1[e] * kw2[(size_t)i * 64 + e];
            int c = i / 9, t = i - c * 9;
            kern_t[((size_t)b * 9 + t) * 128 + c] = s;
        }
    }
}

// -- GroupNorm apply + Swish, NCHW fp32 -> padded NHWC bf16 (LDS transpose) --
__global__ __launch_bounds__(256)
void gn_apply_kernel(const float* __restrict__ x, const float* __restrict__ gamma,
                     const float* __restrict__ beta, const float* __restrict__ stats,
                     u16* __restrict__ hact) {
    __shared__ u16 s_t[128 * 128];
    const int tid = threadIdx.x;
    const int y = blockIdx.x & 127, b = blockIdx.x >> 7;
    #pragma unroll
    for (int i = 0; i < 16; ++i) {
        int unit = (i << 8) + tid;              // (c, x-quad)
        int c = unit >> 5, xq = unit & 31, xx = xq * 4;
        float4 v = *(const float4*)&x[(((size_t)b * 128 + c) * 128 + y) * 128 + xx];
        int gi = b * 32 + (c >> 2);
        float mean = stats[2 * gi], rstd = stats[2 * gi + 1];
        float ga = gamma[c] * rstd, be = beta[c] - mean * ga;
        float a0 = v.x * ga + be, a1 = v.y * ga + be, a2 = v.z * ga + be, a3 = v.w * ga + be;
        a0 = a0 / (1.f + __expf(-a0)); a1 = a1 / (1.f + __expf(-a1));
        a2 = a2 / (1.f + __expf(-a2)); a3 = a3 / (1.f + __expf(-a3));
        int cs = c ^ ((xq & 15) << 3);          // bank swizzle, keeps 8-groups intact
        s_t[(xx + 0) * 128 + cs] = f2bf(a0);
        s_t[(xx + 1) * 128 + cs] = f2bf(a1);
        s_t[(xx + 2) * 128 + cs] = f2bf(a2);
        s_t[(xx + 3) * 128 + cs] = f2bf(a3);
    }
    __syncthreads();
    #pragma unroll
    for (int i = 0; i < 8; ++i) {
        int unit = (i << 8) + tid;              // (x, c-group)
        int xx = unit >> 4, c0 = (unit & 15) * 8;
        int c0s = c0 ^ (((xx >> 2) & 15) << 3);
        u16x8 v = *(const u16x8*)&s_t[xx * 128 + c0s];
        *(u16x8*)&hact[(((size_t)b * PW + y + 1) * PW + (xx + 1)) * 128 + c0] = v;
    }
}

// ---------------- conv1: low-register / high-occupancy variant -------------
// (round-15 verified; 8 waves x (32co x 64px), acc[2][4], 4 waves/SIMD)
__global__ __launch_bounds__(512, 4)
void conv1_mfma_kernel(const u16* __restrict__ act, const u16* __restrict__ wt,
                       const float* __restrict__ bias, u16* __restrict__ outh) {
    __shared__ __align__(16) u16 s_in[2][1024 * 8];

    const int tid = threadIdx.x;
    const int lane = tid & 63, wid = tid >> 6;
    const int wm = wid & 3, wq = wid >> 2;            // co-quarter(32), px-half(64)
    const int l15 = lane & 15, l4 = lane >> 4;

    const int bid0 = blockIdx.x;
    const int bid = ((bid0 & 7) << 8) | (bid0 >> 3);
    const int tx = bid & 7, ty = (bid >> 3) & 15, b = bid >> 7;
    const int x0 = tx * 16, y0 = ty * 8;

    f32x4 acc[2][4];
    #pragma unroll
    for (int mi = 0; mi < 2; ++mi)
        #pragma unroll
        for (int nj = 0; nj < 4; ++nj) acc[mi][nj] = (f32x4)(0.f);

    int in_vofs[2];
    #pragma unroll
    for (int r = 0; r < 2; ++r) {
        int slot = r * 512 + tid;
        if (slot > 719) slot = 719;
        int cik = slot / 180;
        int pos = slot - cik * 180;
        int row = pos / 18, col = pos - row * 18;
        in_vofs[r] = (row * PW + col) * 128 + cik * 8;
    }
    const u16* in_base = act + (((size_t)b * PW + y0) * PW + x0) * 128;

    auto stage_in = [&](int buf, int ci0) {
        #pragma unroll
        for (int r = 0; r < 2; ++r)
            gload_lds16(in_base + ci0 + in_vofs[r],
                        &s_in[buf][(size_t)(r * 512 + (wid << 6)) * 8]);
    };

    const u16* wlane = wt + l4 * 1024 + (wm * 32 + l15) * 8;
    const int bbase = (l4 * 180 + (wq * 4) * 18 + l15) * 8;

    stage_in(0, 0);
    asm volatile("s_waitcnt vmcnt(0)" ::: "memory");
    __builtin_amdgcn_s_barrier();
    __builtin_amdgcn_sched_barrier(0);

    #pragma unroll
    for (int c = 0; c < 4; ++c) {
        if (c > 0) {
            __builtin_amdgcn_s_barrier();
            __builtin_amdgcn_sched_barrier(0);
        }
        if (c < 3) stage_in((c + 1) & 1, (c + 1) * 32);
        __builtin_amdgcn_sched_barrier(0);

        const u16* sb = &s_in[c & 1][0];
        #pragma unroll
        for (int dyr = 0; dyr < 3; ++dyr) {
            #pragma unroll
            for (int dx = 0; dx < 3; ++dx) {
                const u16* wp = wlane + (size_t)(((dyr * 3 + dx) * 4 + c) * 4096);
                bfrag a0 = *(const bfrag*)(wp);
                bfrag a1 = *(const bfrag*)(wp + 128);
                const int bo = bbase + (dyr * 18 + dx) * 8;
                bfrag b0 = *(const bfrag*)&sb[bo];
                bfrag b1 = *(const bfrag*)&sb[bo + 144];
                bfrag b2 = *(const bfrag*)&sb[bo + 288];
                bfrag b3 = *(const bfrag*)&sb[bo + 432];

                __builtin_amdgcn_s_setprio(1);
                acc[0][0] = __builtin_amdgcn_mfma_f32_16x16x32_bf16(a0, b0, acc[0][0], 0, 0, 0);
                acc[0][1] = __builtin_amdgcn_mfma_f32_16x16x32_bf16(a0, b1, acc[0][1], 0, 0, 0);
                acc[0][2] = __builtin_amdgcn_mfma_f32_16x16x32_bf16(a0, b2, acc[0][2], 0, 0, 0);
                acc[0][3] = __builtin_amdgcn_mfma_f32_16x16x32_bf16(a0, b3, acc[0][3], 0, 0, 0);
                acc[1][0] = __builtin_amdgcn_mfma_f32_16x16x32_bf16(a1, b0, acc[1][0], 0, 0, 0);
                acc[1][1] = __builtin_amdgcn_mfma_f32_16x16x32_bf16(a1, b1, acc[1][1], 0, 0, 0);
                acc[1][2] = __builtin_amdgcn_mfma_f32_16x16x32_bf16(a1, b2, acc[1][2], 0, 0, 0);
                acc[1][3] = __builtin_amdgcn_mfma_f32_16x16x32_bf16(a1, b3, acc[1][3], 0, 0, 0);
                __builtin_amdgcn_s_setprio(0);
            }
        }
    }

    const float* bb = bias + b * 128;
    #pragma unroll
    for (int mi = 0; mi < 2; ++mi) {
        const int cb = wm * 32 + mi * 16 + l4 * 4;
        float4 bv4 = *(const float4*)&bb[cb];
        #pragma unroll
        for (int nj = 0; nj < 4; ++nj) {
            int y = y0 + wq * 4 + nj, xx = x0 + l15;
            u16x4 pk;
            pk[0] = f2bf(acc[mi][nj][0] + bv4.x);
            pk[1] = f2bf(acc[mi][nj][1] + bv4.y);
            pk[2] = f2bf(acc[mi][nj][2] + bv4.z);
            pk[3] = f2bf(acc[mi][nj][3] + bv4.w);
            *(u16x4*)&outh[(((size_t)b * PW + y + 1) * PW + (xx + 1)) * 128 + cb] = pk;
        }
    }
}

// ---- conv2 (FINAL): high-occupancy + LDS-handoff fused dw + residual ------
// Same MFMA structure as conv1 (acc[2][4] = 32 regs, no persistent dw regs).
// Per chunk: after the MFMA loop, ALL 8 waves compute dw for the chunk's 32
// channels x 128 px (thread = (px, 8-ch octet); 9 u16x8 s_in reads + 72 FMA),
// apply leaky, write s_dw[32][132]; barrier; owning wave (wm==ck) folds its
// 32 values directly into acc (linear add into MFMA C-regs). No spill.
__global__ __launch_bounds__(512, 4)
void conv2_mfma_kernel(const u16* __restrict__ act, const u16* __restrict__ wt,
                       const float* __restrict__ bias, const float* __restrict__ kern_t,
                       const float* __restrict__ xres, float* __restrict__ outf) {
    __shared__ __align__(16) u16 s_in[2][1024 * 8];   // 32 KB
    __shared__ float s_k[1152];                       // 4.6 KB
    __shared__ float s_dw[32 * 132];                  // 16.9 KB

    const int tid = threadIdx.x;
    const int lane = tid & 63, wid = tid >> 6;
    const int wm = wid & 3, wq = wid >> 2;            // co-quarter(32), px-half(64)
    const int l15 = lane & 15, l4 = lane >> 4;

    const int bid0 = blockIdx.x;
    const int bid = ((bid0 & 7) << 8) | (bid0 >> 3);
    const int tx = bid & 7, ty = (bid >> 3) & 15, b = bid >> 7;
    const int x0 = tx * 16, y0 = ty * 8;

    f32x4 acc[2][4];
    #pragma unroll
    for (int mi = 0; mi < 2; ++mi)
        #pragma unroll
        for (int nj = 0; nj < 4; ++nj) acc[mi][nj] = (f32x4)(0.f);

    for (int i = tid; i < 1152; i += 512) s_k[i] = kern_t[(size_t)b * 1152 + i];
    __syncthreads();                                  // ledger starts clean

    int in_vofs[2];
    #pragma unroll
    for (int r = 0; r < 2; ++r) {
        int slot = r * 512 + tid;
        if (slot > 719) slot = 719;
        int cik = slot / 180;
        int pos = slot - cik * 180;
        int row = pos / 18, col = pos - row * 18;
        in_vofs[r] = (row * PW + col) * 128 + cik * 8;
    }
    const u16* in_base = act + (((size_t)b * PW + y0) * PW + x0) * 128;

    auto stage_in = [&](int buf, int ci0) {
        #pragma unroll
        for (int r = 0; r < 2; ++r)
            gload_lds16(in_base + ci0 + in_vofs[r],
                        &s_in[buf][(size_t)(r * 512 + (wid << 6)) * 8]);
    };

    const u16* wlane = wt + l4 * 1024 + (wm * 32 + l15) * 8;
    const int bbase = (l4 * 180 + (wq * 4) * 18 + l15) * 8;

    // dw producer geometry: thread = (px 0..127, octet 0..3)
    const int dpx = tid & 127, dcg = tid >> 7;
    const int dxx = dpx & 15, dyrow = dpx >> 4;

    stage_in(0, 0);
    asm volatile("s_waitcnt vmcnt(0)" ::: "memory");
    __builtin_amdgcn_s_barrier();
    __builtin_amdgcn_sched_barrier(0);

    #pragma unroll
    for (int c = 0; c < 4; ++c) {
        if (c > 0) {
            __builtin_amdgcn_s_barrier();
            __builtin_amdgcn_sched_barrier(0);
        }
        if (c < 3) {
            stage_in((c + 1) & 1, (c + 1) * 32);
            asm volatile("s_waitcnt vmcnt(2)" ::: "memory");   // drain older stage
        } else {
            asm volatile("s_waitcnt vmcnt(0)" ::: "memory");
        }
        __builtin_amdgcn_sched_barrier(0);

        const u16* sb = &s_in[c & 1][0];
        #pragma unroll
        for (int dyr = 0; dyr < 3; ++dyr) {
            #pragma unroll
            for (int dx = 0; dx < 3; ++dx) {
                const u16* wp = wlane + (size_t)(((dyr * 3 + dx) * 4 + c) * 4096);
                bfrag a0 = *(const bfrag*)(wp);
                bfrag a1 = *(const bfrag*)(wp + 128);
                const int bo = bbase + (dyr * 18 + dx) * 8;
                bfrag b0 = *(const bfrag*)&sb[bo];
                bfrag b1 = *(const bfrag*)&sb[bo + 144];
                bfrag b2 = *(const bfrag*)&sb[bo + 288];
                bfrag b3 = *(const bfrag*)&sb[bo + 432];

                __builtin_amdgcn_s_setprio(1);
                acc[0][0] = __builtin_amdgcn_mfma_f32_16x16x32_bf16(a0, b0, acc[0][0], 0, 0, 0);
                acc[0][1] = __builtin_amdgcn_mfma_f32_16x16x32_bf16(a0, b1, acc[0][1], 0, 0, 0);
                acc[0][2] = __builtin_amdgcn_mfma_f32_16x16x32_bf16(a0, b2, acc[0][2], 0, 0, 0);
                acc[0][3] = __builtin_amdgcn_mfma_f32_16x16x32_bf16(a0, b3, acc[0][3], 0, 0, 0);
                acc[1][0] = __builtin_amdgcn_mfma_f32_16x16x32_bf16(a1, b0, acc[1][0], 0, 0, 0);
                acc[1][1] = __builtin_amdgcn_mfma_f32_16x16x32_bf16(a1, b1, acc[1][1], 0, 0, 0);
                acc[1][2] = __builtin_amdgcn_mfma_f32_16x16x32_bf16(a1, b2, acc[1][2], 0, 0, 0);
                acc[1][3] = __builtin_amdgcn_mfma_f32_16x16x32_bf16(a1, b3, acc[1][3], 0, 0, 0);
                __builtin_amdgcn_s_setprio(0);
            }
        }

        // ---- dw producer: all waves, chunk c's 32 channels x 128 px ----
        {
            float a8[8];
            #pragma unroll
            for (int e = 0; e < 8; ++e) a8[e] = 0.f;
            #pragma unroll
            for (int tap = 0; tap < 9; ++tap) {
                const int dy = tap / 3, dx = tap - dy * 3;
                u16x8 h = *(const u16x8*)
                    &sb[(dcg * 180 + (dyrow + dy) * 18 + (dxx + dx)) * 8];
                const float* kp = &s_k[tap * 128 + c * 32 + dcg * 8];
                float4 k0 = *(const float4*)kp;
                float4 k1 = *(const float4*)(kp + 4);
                a8[0] += bf2f(h[0]) * k0.x;  a8[1] += bf2f(h[1]) * k0.y;
                a8[2] += bf2f(h[2]) * k0.z;  a8[3] += bf2f(h[3]) * k0.w;
                a8[4] += bf2f(h[4]) * k1.x;  a8[5] += bf2f(h[5]) * k1.y;
                a8[6] += bf2f(h[6]) * k1.z;  a8[7] += bf2f(h[7]) * k1.w;
            }
            #pragma unroll
            for (int e = 0; e < 8; ++e) {
                float v = a8[e];
                s_dw[(dcg * 8 + e) * 132 + dpx] = v >= 0.f ? v : NEG * v;
            }
        }
        __builtin_amdgcn_s_barrier();      // s_dw complete for chunk c

        // ---- owner fold: wave wm==c adds leaky(dw) into its acc ----
        if (wm == c) {
            #pragma unroll
            for (int mi = 0; mi < 2; ++mi) {
                #pragma unroll
                for (int nj = 0; nj < 4; ++nj) {
                    const int px = (wq * 4 + nj) * 16 + l15;
                    #pragma unroll
                    for (int j = 0; j < 4; ++j) {
                        const int lc = mi * 16 + l4 * 4 + j;
                        acc[mi][nj][j] += s_dw[lc * 132 + px];
                    }
                }
            }
        }
    }

    // epilogue: out = acc(+dw) + bias + xres (single coalesced write)
    #pragma unroll
    for (int mi = 0; mi < 2; ++mi) {
        const int cb = wm * 32 + mi * 16 + l4 * 4;
        float4 bv4 = *(const float4*)&bias[cb];
        #pragma unroll
        for (int nj = 0; nj < 4; ++nj) {
            int y = y0 + wq * 4 + nj, xx = x0 + l15;
            size_t obase = (((size_t)b * 128 + cb) * 128 + y) * 128 + xx;
            #pragma unroll
            for (int j = 0; j < 4; ++j) {
                float bj = (j == 0) ? bv4.x : (j == 1) ? bv4.y : (j == 2) ? bv4.z : bv4.w;
                outf[obase + (size_t)j * 16384] =
                    acc[mi][nj][j] + bj + xres[obase + (size_t)j * 16384];
            }
        }
    }
}

extern "C" void kernel_launch(void* const* d_in, const int* in_sizes, int n_in,
                              void* d_out, int out_size, void* d_ws, size_t ws_size,
                              hipStream_t stream) {
    const float* x        = (const float*)d_in[0];
    const float* te       = (const float*)d_in[1];
    const float* kv       = (const float*)d_in[2];
    const float* gn1_g    = (const float*)d_in[3];
    const float* gn1_b    = (const float*)d_in[4];
    const float* conv1_w  = (const float*)d_in[5];
    const float* conv1_b  = (const float*)d_in[6];
    const float* nf_w     = (const float*)d_in[7];
    const float* nf_b     = (const float*)d_in[8];
    const float* kW1      = (const float*)d_in[9];
    const float* kW2      = (const float*)d_in[10];
    const float* daconv_w = (const float*)d_in[11];
    const float* daconv_b = (const float*)d_in[12];

    float* out = (float*)d_out;

    // workspace: kern_t, w2t, hbuf (padded)
    float* kern  = (float*)d_ws;                         // 18432 f32 ([b][tap][c])
    u16*   w2t   = (u16*)(kern + 18432);                 // 147456 u16
    u16*   hbuf  = (u16*)(kern + 92160);                 // 16*130*130*128 u16 (69.2 MB)

    // temps dead before conv2's overwrite of d_out
    u16*   hact    = (u16*)out;                          // padded NHWC
    float* up      = out + 17500160;
    float* stats   = up;                                 // 1024
    float* biastot = up + 1024;                          // 2048
    u16*   w1t     = (u16*)(up + 4096);                  // 147456 u16

    prep_kernel<<<dim3(1628), dim3(256), 0, stream>>>(
        x, stats, conv1_w, daconv_w, w1t, w2t, hact, hbuf,
        te, nf_w, nf_b, conv1_b, biastot, kv, kW1, kW2, kern);
    gn_apply_kernel<<<dim3(2048), dim3(256), 0, stream>>>(x, gn1_g, gn1_b, stats, hact);
    conv1_mfma_kernel<<<dim3(2048), dim3(512), 0, stream>>>(hact, w1t, biastot, hbuf);
    conv2_mfma_kernel<<<dim3(2048), dim3(512), 0, stream>>>(
        hbuf, w2t, daconv_b, kern, x, out);
}

// Round 18
// 281.078 us; speedup vs baseline: 1.3329x; 1.2778x over previous
//
#include <hip/hip_runtime.h>
#include <hip/hip_bf16.h>
#include <math.h>
#include <stdint.h>

typedef unsigned short u16;
typedef __attribute__((ext_vector_type(8))) short bfrag;      // 8 bf16 = 4 VGPR
typedef __attribute__((ext_vector_type(4))) float f32x4;
typedef __attribute__((ext_vector_type(8))) unsigned short u16x8;
typedef __attribute__((ext_vector_type(4))) unsigned short u16x4;

#define BB 16
#define CC 128
#define HH 128
#define WW 128
#define EPSV 1e-5f
#define NEG 0.1f
#define PW 130           // padded width/height (1-px zero border)

__device__ __forceinline__ float bf2f(u16 u) {
    unsigned int x = ((unsigned int)u) << 16;
    return __builtin_bit_cast(float, x);
}
__device__ __forceinline__ u16 f2bf(float f) {   // RNE
    unsigned int x = __builtin_bit_cast(unsigned int, f);
    unsigned int r = x + 0x7fffu + ((x >> 16) & 1u);
    return (u16)(r >> 16);
}
__device__ __forceinline__ void gload_lds16(const void* g, void* l) {
    __builtin_amdgcn_global_load_lds(
        (const __attribute__((address_space(1))) void*)g,
        (__attribute__((address_space(3))) void*)l, 16, 0, 0);
}

// ---------------- merged prep kernel -----------------------------------
__global__ __launch_bounds__(256)
void prep_kernel(const float* __restrict__ x, float* __restrict__ stats,
                 const float* __restrict__ w1, const float* __restrict__ w2,
                 u16* __restrict__ w1t, u16* __restrict__ w2t,
                 u16* __restrict__ hact, u16* __restrict__ hbuf,
                 const float* __restrict__ te, const float* __restrict__ nfw,
                 const float* __restrict__ nfbias, const float* __restrict__ c1b,
                 float* __restrict__ biastot,
                 const float* __restrict__ kv, const float* __restrict__ kw1,
                 const float* __restrict__ kw2, float* __restrict__ kern_t) {
    __shared__ float rs[8];
    __shared__ float s_t1[64];
    const int blk = blockIdx.x;
    const int tid = threadIdx.x;

    if (blk < 512) {                                    // ---- gn_stats ----
        const int bg = blk;
        const float* base = x + (size_t)bg * 65536;
        float s1 = 0.f, s2 = 0.f;
        for (int i = tid; i < 16384; i += 256) {
            float4 v = *(const float4*)&base[i * 4];
            s1 += v.x + v.y + v.z + v.w;
            s2 += v.x * v.x + v.y * v.y + v.z * v.z + v.w * v.w;
        }
        #pragma unroll
        for (int off = 32; off > 0; off >>= 1) {
            s1 += __shfl_down(s1, off);
            s2 += __shfl_down(s2, off);
        }
        const int wid = tid >> 6, lane = tid & 63;
        if (lane == 0) { rs[wid * 2] = s1; rs[wid * 2 + 1] = s2; }
        __syncthreads();
        if (tid == 0) {
            s1 = rs[0] + rs[2] + rs[4] + rs[6];
            s2 = rs[1] + rs[3] + rs[5] + rs[7];
            float mean = s1 * (1.f / 65536.f);
            float var  = s2 * (1.f / 65536.f) - mean * mean;
            stats[2 * bg]     = mean;
            stats[2 * bg + 1] = rsqrtf(var + EPSV);
        }
    } else if (blk < 1088) {                            // ---- wconv ----
        int idx = (blk - 512) * 256 + tid;              // < 147456
        int e  = idx & 7;
        int co = (idx >> 3) & 127;
        int g  = (idx >> 10) & 3;
        int ck = (idx >> 12) & 3;
        int t  = idx >> 14;
        int src = (co * 128 + (ck * 32 + g * 8 + e)) * 9 + t;
        w1t[idx] = f2bf(w1[src]);
        w2t[idx] = f2bf(w2[src]);
    } else if (blk < 1604) {                            // ---- border ----
        int idx = (blk - 1088) * 256 + tid;             // < 132096
        int cg = idx & 15;
        int t = idx >> 4;
        int b = t / 516, e = t - b * 516;
        int y, xx;
        if (e < 130)      { y = 0;           xx = e; }
        else if (e < 260) { y = 129;         xx = e - 130; }
        else if (e < 388) { y = e - 260 + 1; xx = 0; }
        else              { y = e - 388 + 1; xx = 129; }
        size_t o = (((size_t)b * PW + y) * PW + xx) * 128 + cg * 8;
        u16x8 z = (u16x8)(u16)0;
        *(u16x8*)&hact[o] = z;
        *(u16x8*)&hbuf[o] = z;
    } else if (blk < 1612) {                            // ---- biastot ----
        int idx = (blk - 1604) * 256 + tid;             // < 2048
        const int b = idx >> 7, c = idx & 127;
        float s = nfbias[c] + c1b[c];
        for (int e = 0; e < 128; ++e) s += te[b * 128 + e] * nfw[c * 128 + e];
        biastot[idx] = s;
    } else {                                            // ---- kern_t ----
        const int b = blk - 1612;                       // one block per b
        if (tid < 64) {
            float s = 0.f;
            for (int e = 0; e < 64; ++e) s += kv[b * 64 + e] * kw1[tid * 64 + e];
            s_t1[tid] = s >= 0.f ? s : NEG * s;
        }
        __syncthreads();
        for (int i = tid; i < 1152; i += 256) {
            float s = 0.f;
            for (int e = 0; e < 64; ++e) s += s_t1[e] * kw2[(size_t)i * 64 + e];
            int c = i / 9, t = i - c * 9;
            kern_t[((size_t)b * 9 + t) * 128 + c] = s;
        }
    }
}

// -- GroupNorm apply + Swish, NCHW fp32 -> padded NHWC bf16 (LDS transpose) --
__global__ __launch_bounds__(256)
void gn_apply_kernel(const float* __restrict__ x, const float* __restrict__ gamma,
                     const float* __restrict__ beta, const float* __restrict__ stats,
                     u16* __restrict__ hact) {
    __shared__ u16 s_t[128 * 128];
    const int tid = threadIdx.x;
    const int y = blockIdx.x & 127, b = blockIdx.x >> 7;
    #pragma unroll
    for (int i = 0; i < 16; ++i) {
        int unit = (i << 8) + tid;              // (c, x-quad)
        int c = unit >> 5, xq = unit & 31, xx = xq * 4;
        float4 v = *(const float4*)&x[(((size_t)b * 128 + c) * 128 + y) * 128 + xx];
        int gi = b * 32 + (c >> 2);
        float mean = stats[2 * gi], rstd = stats[2 * gi + 1];
        float ga = gamma[c] * rstd, be = beta[c] - mean * ga;
        float a0 = v.x * ga + be, a1 = v.y * ga + be, a2 = v.z * ga + be, a3 = v.w * ga + be;
        a0 = a0 / (1.f + __expf(-a0)); a1 = a1 / (1.f + __expf(-a1));
        a2 = a2 / (1.f + __expf(-a2)); a3 = a3 / (1.f + __expf(-a3));
        int cs = c ^ ((xq & 15) << 3);          // bank swizzle, keeps 8-groups intact
        s_t[(xx + 0) * 128 + cs] = f2bf(a0);
        s_t[(xx + 1) * 128 + cs] = f2bf(a1);
        s_t[(xx + 2) * 128 + cs] = f2bf(a2);
        s_t[(xx + 3) * 128 + cs] = f2bf(a3);
    }
    __syncthreads();
    #pragma unroll
    for (int i = 0; i < 8; ++i) {
        int unit = (i << 8) + tid;              // (x, c-group)
        int xx = unit >> 4, c0 = (unit & 15) * 8;
        int c0s = c0 ^ (((xx >> 2) & 15) << 3);
        u16x8 v = *(const u16x8*)&s_t[xx * 128 + c0s];
        *(u16x8*)&hact[(((size_t)b * PW + y + 1) * PW + (xx + 1)) * 128 + c0] = v;
    }
}

// ---------------- conv1: low-register / high-occupancy variant -------------
// (round-15 verified; 8 waves x (32co x 64px), acc[2][4], 4 waves/SIMD)
__global__ __launch_bounds__(512, 4)
void conv1_mfma_kernel(const u16* __restrict__ act, const u16* __restrict__ wt,
                       const float* __restrict__ bias, u16* __restrict__ outh) {
    __shared__ __align__(16) u16 s_in[2][1024 * 8];

    const int tid = threadIdx.x;
    const int lane = tid & 63, wid = tid >> 6;
    const int wm = wid & 3, wq = wid >> 2;            // co-quarter(32), px-half(64)
    const int l15 = lane & 15, l4 = lane >> 4;

    const int bid0 = blockIdx.x;
    const int bid = ((bid0 & 7) << 8) | (bid0 >> 3);
    const int tx = bid & 7, ty = (bid >> 3) & 15, b = bid >> 7;
    const int x0 = tx * 16, y0 = ty * 8;

    f32x4 acc[2][4];
    #pragma unroll
    for (int mi = 0; mi < 2; ++mi)
        #pragma unroll
        for (int nj = 0; nj < 4; ++nj) acc[mi][nj] = (f32x4)(0.f);

    int in_vofs[2];
    #pragma unroll
    for (int r = 0; r < 2; ++r) {
        int slot = r * 512 + tid;
        if (slot > 719) slot = 719;
        int cik = slot / 180;
        int pos = slot - cik * 180;
        int row = pos / 18, col = pos - row * 18;
        in_vofs[r] = (row * PW + col) * 128 + cik * 8;
    }
    const u16* in_base = act + (((size_t)b * PW + y0) * PW + x0) * 128;

    auto stage_in = [&](int buf, int ci0) {
        #pragma unroll
        for (int r = 0; r < 2; ++r)
            gload_lds16(in_base + ci0 + in_vofs[r],
                        &s_in[buf][(size_t)(r * 512 + (wid << 6)) * 8]);
    };

    const u16* wlane = wt + l4 * 1024 + (wm * 32 + l15) * 8;
    const int bbase = (l4 * 180 + (wq * 4) * 18 + l15) * 8;

    stage_in(0, 0);
    asm volatile("s_waitcnt vmcnt(0)" ::: "memory");
    __builtin_amdgcn_s_barrier();
    __builtin_amdgcn_sched_barrier(0);

    #pragma unroll
    for (int c = 0; c < 4; ++c) {
        if (c > 0) {
            __builtin_amdgcn_s_barrier();
            __builtin_amdgcn_sched_barrier(0);
        }
        if (c < 3) stage_in((c + 1) & 1, (c + 1) * 32);
        __builtin_amdgcn_sched_barrier(0);

        const u16* sb = &s_in[c & 1][0];
        #pragma unroll
        for (int dyr = 0; dyr < 3; ++dyr) {
            #pragma unroll
            for (int dx = 0; dx < 3; ++dx) {
                const u16* wp = wlane + (size_t)(((dyr * 3 + dx) * 4 + c) * 4096);
                bfrag a0 = *(const bfrag*)(wp);
                bfrag a1 = *(const bfrag*)(wp + 128);
                const int bo = bbase + (dyr * 18 + dx) * 8;
                bfrag b0 = *(const bfrag*)&sb[bo];
                bfrag b1 = *(const bfrag*)&sb[bo + 144];
                bfrag b2 = *(const bfrag*)&sb[bo + 288];
                bfrag b3 = *(const bfrag*)&sb[bo + 432];

                __builtin_amdgcn_s_setprio(1);
                acc[0][0] = __builtin_amdgcn_mfma_f32_16x16x32_bf16(a0, b0, acc[0][0], 0, 0, 0);
                acc[0][1] = __builtin_amdgcn_mfma_f32_16x16x32_bf16(a0, b1, acc[0][1], 0, 0, 0);
                acc[0][2] = __builtin_amdgcn_mfma_f32_16x16x32_bf16(a0, b2, acc[0][2], 0, 0, 0);
                acc[0][3] = __builtin_amdgcn_mfma_f32_16x16x32_bf16(a0, b3, acc[0][3], 0, 0, 0);
                acc[1][0] = __builtin_amdgcn_mfma_f32_16x16x32_bf16(a1, b0, acc[1][0], 0, 0, 0);
                acc[1][1] = __builtin_amdgcn_mfma_f32_16x16x32_bf16(a1, b1, acc[1][1], 0, 0, 0);
                acc[1][2] = __builtin_amdgcn_mfma_f32_16x16x32_bf16(a1, b2, acc[1][2], 0, 0, 0);
                acc[1][3] = __builtin_amdgcn_mfma_f32_16x16x32_bf16(a1, b3, acc[1][3], 0, 0, 0);
                __builtin_amdgcn_s_setprio(0);
            }
        }
    }

    const float* bb = bias + b * 128;
    #pragma unroll
    for (int mi = 0; mi < 2; ++mi) {
        const int cb = wm * 32 + mi * 16 + l4 * 4;
        float4 bv4 = *(const float4*)&bb[cb];
        #pragma unroll
        for (int nj = 0; nj < 4; ++nj) {
            int y = y0 + wq * 4 + nj, xx = x0 + l15;
            u16x4 pk;
            pk[0] = f2bf(acc[mi][nj][0] + bv4.x);
            pk[1] = f2bf(acc[mi][nj][1] + bv4.y);
            pk[2] = f2bf(acc[mi][nj][2] + bv4.z);
            pk[3] = f2bf(acc[mi][nj][3] + bv4.w);
            *(u16x4*)&outh[(((size_t)b * PW + y + 1) * PW + (xx + 1)) * 128 + cb] = pk;
        }
    }
}

// ---- conv2 (FINAL): high-occupancy + LDS-handoff fused dw + residual ------
// dw producer slimmed to 4-channel quads x 2 passes (~12 live regs) so the
// whole kernel fits the 64-VGPR budget at (512,4) without spilling.
__global__ __launch_bounds__(512, 4)
void conv2_mfma_kernel(const u16* __restrict__ act, const u16* __restrict__ wt,
                       const float* __restrict__ bias, const float* __restrict__ kern_t,
                       const float* __restrict__ xres, float* __restrict__ outf) {
    __shared__ __align__(16) u16 s_in[2][1024 * 8];   // 32 KB
    __shared__ float s_k[1152];                       // 4.6 KB
    __shared__ float s_dw[32 * 132];                  // 16.9 KB

    const int tid = threadIdx.x;
    const int lane = tid & 63, wid = tid >> 6;
    const int wm = wid & 3, wq = wid >> 2;            // co-quarter(32), px-half(64)
    const int l15 = lane & 15, l4 = lane >> 4;

    const int bid0 = blockIdx.x;
    const int bid = ((bid0 & 7) << 8) | (bid0 >> 3);
    const int tx = bid & 7, ty = (bid >> 3) & 15, b = bid >> 7;
    const int x0 = tx * 16, y0 = ty * 8;

    f32x4 acc[2][4];
    #pragma unroll
    for (int mi = 0; mi < 2; ++mi)
        #pragma unroll
        for (int nj = 0; nj < 4; ++nj) acc[mi][nj] = (f32x4)(0.f);

    for (int i = tid; i < 1152; i += 512) s_k[i] = kern_t[(size_t)b * 1152 + i];
    __syncthreads();                                  // ledger starts clean

    int in_vofs[2];
    #pragma unroll
    for (int r = 0; r < 2; ++r) {
        int slot = r * 512 + tid;
        if (slot > 719) slot = 719;
        int cik = slot / 180;
        int pos = slot - cik * 180;
        int row = pos / 18, col = pos - row * 18;
        in_vofs[r] = (row * PW + col) * 128 + cik * 8;
    }
    const u16* in_base = act + (((size_t)b * PW + y0) * PW + x0) * 128;

    auto stage_in = [&](int buf, int ci0) {
        #pragma unroll
        for (int r = 0; r < 2; ++r)
            gload_lds16(in_base + ci0 + in_vofs[r],
                        &s_in[buf][(size_t)(r * 512 + (wid << 6)) * 8]);
    };

    const u16* wlane = wt + l4 * 1024 + (wm * 32 + l15) * 8;
    const int bbase = (l4 * 180 + (wq * 4) * 18 + l15) * 8;

    // dw producer geometry: thread = (px 0..127, quad q 0..3); 2 passes
    const int dpx = tid & 127, dq = tid >> 7;
    const int dxx = dpx & 15, dyrow = dpx >> 4;
    const int dcik_lo = dq >> 1;                     // within 16-ch half
    const int de0 = (dq & 1) * 4;

    stage_in(0, 0);
    asm volatile("s_waitcnt vmcnt(0)" ::: "memory");
    __builtin_amdgcn_s_barrier();
    __builtin_amdgcn_sched_barrier(0);

    #pragma unroll
    for (int c = 0; c < 4; ++c) {
        if (c > 0) {
            __builtin_amdgcn_s_barrier();
            __builtin_amdgcn_sched_barrier(0);
        }
        if (c < 3) {
            stage_in((c + 1) & 1, (c + 1) * 32);
            asm volatile("s_waitcnt vmcnt(2)" ::: "memory");   // drain older stage
        } else {
            asm volatile("s_waitcnt vmcnt(0)" ::: "memory");
        }
        __builtin_amdgcn_sched_barrier(0);

        const u16* sb = &s_in[c & 1][0];
        #pragma unroll
        for (int dyr = 0; dyr < 3; ++dyr) {
            #pragma unroll
            for (int dx = 0; dx < 3; ++dx) {
                const u16* wp = wlane + (size_t)(((dyr * 3 + dx) * 4 + c) * 4096);
                bfrag a0 = *(const bfrag*)(wp);
                bfrag a1 = *(const bfrag*)(wp + 128);
                const int bo = bbase + (dyr * 18 + dx) * 8;
                bfrag b0 = *(const bfrag*)&sb[bo];
                bfrag b1 = *(const bfrag*)&sb[bo + 144];
                bfrag b2 = *(const bfrag*)&sb[bo + 288];
                bfrag b3 = *(const bfrag*)&sb[bo + 432];

                __builtin_amdgcn_s_setprio(1);
                acc[0][0] = __builtin_amdgcn_mfma_f32_16x16x32_bf16(a0, b0, acc[0][0], 0, 0, 0);
                acc[0][1] = __builtin_amdgcn_mfma_f32_16x16x32_bf16(a0, b1, acc[0][1], 0, 0, 0);
                acc[0][2] = __builtin_amdgcn_mfma_f32_16x16x32_bf16(a0, b2, acc[0][2], 0, 0, 0);
                acc[0][3] = __builtin_amdgcn_mfma_f32_16x16x32_bf16(a0, b3, acc[0][3], 0, 0, 0);
                acc[1][0] = __builtin_amdgcn_mfma_f32_16x16x32_bf16(a1, b0, acc[1][0], 0, 0, 0);
                acc[1][1] = __builtin_amdgcn_mfma_f32_16x16x32_bf16(a1, b1, acc[1][1], 0, 0, 0);
                acc[1][2] = __builtin_amdgcn_mfma_f32_16x16x32_bf16(a1, b2, acc[1][2], 0, 0, 0);
                acc[1][3] = __builtin_amdgcn_mfma_f32_16x16x32_bf16(a1, b3, acc[1][3], 0, 0, 0);
                __builtin_amdgcn_s_setprio(0);
            }
        }
        __builtin_amdgcn_sched_barrier(0);   // fence MFMA live-ranges from dw

        // ---- dw producer: 2 passes of 4-ch quads (low register pressure) ----
        #pragma unroll
        for (int qh = 0; qh < 2; ++qh) {
            const int cik = qh * 2 + dcik_lo;
            float a4[4];
            #pragma unroll
            for (int e = 0; e < 4; ++e) a4[e] = 0.f;
            #pragma unroll
            for (int tap = 0; tap < 9; ++tap) {
                const int dy = tap / 3, dx = tap - dy * 3;
                u16x4 h = *(const u16x4*)
                    &sb[(cik * 180 + (dyrow + dy) * 18 + (dxx + dx)) * 8 + de0];
                float4 kk = *(const float4*)&s_k[tap * 128 + c * 32 + qh * 16 + dq * 4];
                a4[0] += bf2f(h[0]) * kk.x;
                a4[1] += bf2f(h[1]) * kk.y;
                a4[2] += bf2f(h[2]) * kk.z;
                a4[3] += bf2f(h[3]) * kk.w;
            }
            #pragma unroll
            for (int e = 0; e < 4; ++e) {
                float v = a4[e];
                s_dw[(qh * 16 + dq * 4 + e) * 132 + dpx] = v >= 0.f ? v : NEG * v;
            }
        }
        __builtin_amdgcn_s_barrier();      // s_dw complete for chunk c
        __builtin_amdgcn_sched_barrier(0);

        // ---- owner fold: wave wm==c adds leaky(dw) into its acc ----
        if (wm == c) {
            #pragma unroll
            for (int mi = 0; mi < 2; ++mi) {
                #pragma unroll
                for (int nj = 0; nj < 4; ++nj) {
                    const int px = (wq * 4 + nj) * 16 + l15;
                    #pragma unroll
                    for (int j = 0; j < 4; ++j) {
                        const int lc = mi * 16 + l4 * 4 + j;
                        acc[mi][nj][j] += s_dw[lc * 132 + px];
                    }
                }
            }
        }
    }

    // epilogue: out = acc(+dw) + bias + xres (single coalesced write)
    #pragma unroll
    for (int mi = 0; mi < 2; ++mi) {
        const int cb = wm * 32 + mi * 16 + l4 * 4;
        float4 bv4 = *(const float4*)&bias[cb];
        #pragma unroll
        for (int nj = 0; nj < 4; ++nj) {
            int y = y0 + wq * 4 + nj, xx = x0 + l15;
            size_t obase = (((size_t)b * 128 + cb) * 128 + y) * 128 + xx;
            #pragma unroll
            for (int j = 0; j < 4; ++j) {
                float bj = (j == 0) ? bv4.x : (j == 1) ? bv4.y : (j == 2) ? bv4.z : bv4.w;
                outf[obase + (size_t)j * 16384] =
                    acc[mi][nj][j] + bj + xres[obase + (size_t)j * 16384];
            }
        }
    }
}

extern "C" void kernel_launch(void* const* d_in, const int* in_sizes, int n_in,
                              void* d_out, int out_size, void* d_ws, size_t ws_size,
                              hipStream_t stream) {
    const float* x        = (const float*)d_in[0];
    const float* te       = (const float*)d_in[1];
    const float* kv       = (const float*)d_in[2];
    const float* gn1_g    = (const float*)d_in[3];
    const float* gn1_b    = (const float*)d_in[4];
    const float* conv1_w  = (const float*)d_in[5];
    const float* conv1_b  = (const float*)d_in[6];
    const float* nf_w     = (const float*)d_in[7];
    const float* nf_b     = (const float*)d_in[8];
    const float* kW1      = (const float*)d_in[9];
    const float* kW2      = (const float*)d_in[10];
    const float* daconv_w = (const float*)d_in[11];
    const float* daconv_b = (const float*)d_in[12];

    float* out = (float*)d_out;

    // workspace: kern_t, w2t, hbuf (padded)
    float* kern  = (float*)d_ws;                         // 18432 f32 ([b][tap][c])
    u16*   w2t   = (u16*)(kern + 18432);                 // 147456 u16
    u16*   hbuf  = (u16*)(kern + 92160);                 // 16*130*130*128 u16 (69.2 MB)

    // temps dead before conv2's overwrite of d_out
    u16*   hact    = (u16*)out;                          // padded NHWC
    float* up      = out + 17500160;
    float* stats   = up;                                 // 1024
    float* biastot = up + 1024;                          // 2048
    u16*   w1t     = (u16*)(up + 4096);                  // 147456 u16

    prep_kernel<<<dim3(1628), dim3(256), 0, stream>>>(
        x, stats, conv1_w, daconv_w, w1t, w2t, hact, hbuf,
        te, nf_w, nf_b, conv1_b, biastot, kv, kW1, kW2, kern);
    gn_apply_kernel<<<dim3(2048), dim3(256), 0, stream>>>(x, gn1_g, gn1_b, stats, hact);
    conv1_mfma_kernel<<<dim3(2048), dim3(512), 0, stream>>>(hact, w1t, biastot, hbuf);
    conv2_mfma_kernel<<<dim3(2048), dim3(512), 0, stream>>>(
        hbuf, w2t, daconv_b, kern, x, out);
}